// Round 7
// baseline (716.132 us; speedup 1.0000x reference)
//
#include <hip/hip_runtime.h>
#include <cstdint>

// B=16, C=64, H=W=256. 3x3 convs via bf16 MFMA implicit GEMM.
// Round 7: conv1 (fW1, leaky -> f1 NHWC bf16) and conv3 (cW, +cb -> fp32 NCHW
// d_out) merged into one kernel: same input staging feeds both A-operands,
// doubling MFMA per staged byte. conv2 unchanged; k_fin unchanged.
// ws reuse: f1 -> ws region2; f2 -> xbf region (dead after k_conv13).
using short8  = __attribute__((ext_vector_type(8))) short;
using short4v = __attribute__((ext_vector_type(4))) short;
using f32x16  = __attribute__((ext_vector_type(16))) float;
using float4v = __attribute__((ext_vector_type(4))) float;
typedef unsigned short ushort_t;

__device__ __forceinline__ float lrelu(float x) { return x > 0.f ? x : 0.1f * x; }

__device__ __forceinline__ ushort_t f2bf(float f) {
    union { float f; unsigned u; } v; v.f = f;
    unsigned r = (v.u + 0x7FFFu + ((v.u >> 16) & 1u)) >> 16;
    return (ushort_t)r;
}
__device__ __forceinline__ float bf2f(ushort_t b) {
    union { unsigned u; float f; } v; v.u = ((unsigned)b) << 16; return v.f;
}

// async 16B global -> LDS (dest = wave-uniform base + lane*16)
__device__ __forceinline__ void gload_lds16(const ushort_t* g, ushort_t* l) {
    __builtin_amdgcn_global_load_lds(
        (const __attribute__((address_space(1))) void*)g,
        (__attribute__((address_space(3))) void*)l, 16, 0, 0);
}

// ---------------------------------------------------------------------------
// Tiny branch: ktr[b][tap][c] = leaky(kern) * sigmoid-gate (mv folded in).
// ---------------------------------------------------------------------------
__global__ void k_tiny(const float* __restrict__ t, const float* __restrict__ tW1,
                       const float* __restrict__ tW2, const float* __restrict__ kW1,
                       const float* __restrict__ kW2, float* __restrict__ ktr) {
    int b = blockIdx.x;
    int c = threadIdx.x;  // 64
    __shared__ float h1[64], g1[64];
    float ts = t[b];
    h1[c] = lrelu(ts * tW1[c]);
    g1[c] = lrelu(ts * kW1[c]);
    __syncthreads();
    float s = 0.f;
    for (int j = 0; j < 64; ++j) s = fmaf(tW2[c * 64 + j], h1[j], s);
    float mvv = 1.f / (1.f + expf(-s));
    for (int q = 0; q < 9; ++q) {
        float s2 = 0.f;
        for (int j = 0; j < 64; ++j) s2 = fmaf(kW2[(c * 9 + q) * 64 + j], g1[j], s2);
        ktr[b * 576 + q * 64 + c] = lrelu(s2) * mvv;
    }
}

// ---------------------------------------------------------------------------
// Zero row buffer (edge-redirect source for staging).
// ---------------------------------------------------------------------------
__global__ void k_zrow(ushort_t* __restrict__ z) {
    int i = blockIdx.x * 256 + threadIdx.x;  // 2048 threads, 16384 shorts
    *(short8*)(z + (size_t)i * 8) = (short8)0;
}

// ---------------------------------------------------------------------------
// Pack three 64x64x3x3 weight tensors into MFMA A-fragment order (bf16).
// flat = (((t*2+ch)*2+kc)*2+ct)*512 + lane*8 + j
//   = W[co = ct*32 + (lane&31)][ci = ch*32 + kc*16 + (lane>>5)*8 + j], tap t
// ---------------------------------------------------------------------------
__global__ void k_pack(const float* __restrict__ w1, const float* __restrict__ w2,
                       const float* __restrict__ w3, ushort_t* __restrict__ wp) {
    int idx = blockIdx.x * 256 + threadIdx.x;
    if (idx >= 3 * 36864) return;
    int conv = idx / 36864, r = idx % 36864;
    const float* W = conv == 0 ? w1 : (conv == 1 ? w2 : w3);
    int j = r & 7, lane = (r >> 3) & 63, ct = (r >> 9) & 1, kc = (r >> 10) & 1,
        ch = (r >> 11) & 1, t = r >> 12;
    int co = ct * 32 + (lane & 31);
    int ci = ch * 32 + kc * 16 + (lane >> 5) * 8 + j;
    wp[idx] = f2bf(W[(co * 64 + ci) * 9 + t]);
}

// ---------------------------------------------------------------------------
// Transpose x: fp32 NCHW -> bf16 NHWC (width-256 rows). Block = (b,h).
// ---------------------------------------------------------------------------
__global__ __launch_bounds__(256) void k_tr(const float* __restrict__ x,
                                            ushort_t* __restrict__ xbf) {
    int bid = blockIdx.x;
    int h = bid & 255, b = bid >> 8;
    int t = threadIdx.x;
    for (int it = 0; it < 8; ++it) {
        int idx = t + it * 256;  // (w, g)
        int g = idx & 7, w = idx >> 3;
        const float* src = x + (((size_t)(b * 64 + g * 8) * 256 + h) * 256 + w);
        short8 v;
#pragma unroll
        for (int j = 0; j < 8; ++j) v[j] = (short)f2bf(src[(size_t)j * 65536]);
        *(short8*)(xbf + (((size_t)(b * 256 + h) * 256 + w) * 64 + g * 8)) = v;
    }
}

// ---------------------------------------------------------------------------
// Merged conv1+conv3: one staging pass feeds two weight sets.
//   accA: fW1 conv -> leaky -> f1 (bf16 NHWC)
//   accC: cW conv + cb -> fp32 NCHW (d_out)
// Block = (b,h) XCD-swizzled; 4 waves x (64 c_out x 64 pix); LDS 50176 B.
// ---------------------------------------------------------------------------
__global__ __launch_bounds__(256, 3) void k_conv13(
    const ushort_t* __restrict__ in, const ushort_t* __restrict__ zv,
    const ushort_t* __restrict__ wpa, const ushort_t* __restrict__ wpc,
    const float* __restrict__ ba, const float* __restrict__ bc,
    ushort_t* __restrict__ f1out, float* __restrict__ cres) {
    __shared__ __align__(16) ushort_t xs[3136 * 8];  // 50176 B
    const int tid = threadIdx.x;
    const int lane = tid & 63;
    const int wv = tid >> 6;
    const unsigned bid = blockIdx.x;
    const unsigned L = (bid & 7u) * 512u + (bid >> 3);
    const int h = L & 255, b = L >> 8;
    const int l31 = lane & 31, lhi = lane >> 5;
    const int pw0 = wv * 64;

    const ushort_t* rb0 = (h > 0)   ? in + ((size_t)(b * 256 + h - 1)) * 16384 : zv;
    const ushort_t* rb1 =             in + ((size_t)(b * 256 + h)) * 16384;
    const ushort_t* rb2 = (h < 255) ? in + ((size_t)(b * 256 + h + 1)) * 16384 : zv;

    f32x16 accA[2][2], accC[2][2];
#pragma unroll
    for (int a = 0; a < 2; ++a)
#pragma unroll
        for (int c = 0; c < 2; ++c) { accA[a][c] = (f32x16)0.0f; accC[a][c] = (f32x16)0.0f; }

    for (int ch = 0; ch < 2; ++ch) {
        __syncthreads();
#pragma unroll
        for (int it = 0; it < 13; ++it) {
            int base = it * 256 + wv * 64;
            if (base < 3120) {
                int S = base + lane;
                S = S < 3120 ? S : 3119;
                int r = (S >= 2080) ? 2 : (S >= 1040 ? 1 : 0);
                int rem = S - r * 1040;
                int m = rem >> 3, sl = rem & 7;
                int sp = sl ^ (m & 7);
                int p = 2 * m + (sp >> 2), g = sp & 3;
                int ws = p - 1;
                bool edge = (unsigned)ws >= 256u;
                const ushort_t* rp = (r == 0) ? rb0 : (r == 1 ? rb1 : rb2);
                const ushort_t* src = edge ? zv : (rp + ws * 64 + ch * 32 + g * 8);
                gload_lds16(src, xs + (size_t)base * 8);
            }
        }
        asm volatile("s_waitcnt vmcnt(0)" ::: "memory");
        __syncthreads();

#pragma unroll
        for (int t = 0; t < 9; ++t) {
            const int dw = t % 3;
            const int rr = t / 3;
#pragma unroll
            for (int kc = 0; kc < 2; ++kc) {
                const int off = ((((t * 2 + ch) * 2 + kc) * 2) * 64 + lane) * 8;
                short8 a0 = *(const short8*)(wpa + off);
                short8 a1 = *(const short8*)(wpa + off + 512);
                short8 c0 = *(const short8*)(wpc + off);
                short8 c1 = *(const short8*)(wpc + off + 512);
                const int g = kc * 2 + lhi;
#pragma unroll
                for (int pt = 0; pt < 2; ++pt) {
                    int p = pw0 + pt * 32 + l31 + dw;
                    int slot = ((p & 1) * 4 + g) ^ ((p >> 1) & 7);
                    short8 bf = *(const short8*)(xs + (((size_t)rr * 130 + (p >> 1)) * 8 + slot) * 8);
                    accA[0][pt] = __builtin_amdgcn_mfma_f32_32x32x16_bf16(a0, bf, accA[0][pt], 0, 0, 0);
                    accA[1][pt] = __builtin_amdgcn_mfma_f32_32x32x16_bf16(a1, bf, accA[1][pt], 0, 0, 0);
                    accC[0][pt] = __builtin_amdgcn_mfma_f32_32x32x16_bf16(c0, bf, accC[0][pt], 0, 0, 0);
                    accC[1][pt] = __builtin_amdgcn_mfma_f32_32x32x16_bf16(c1, bf, accC[1][pt], 0, 0, 0);
                }
            }
        }
    }

    // Epilogues. D layout: col(pix)=lane&31, row(co)=(reg&3)+8*(reg>>2)+4*(lane>>5)
    const int co_b = 4 * lhi;
    {   // conv1 -> bf16 NHWC + leaky
        ushort_t* outb = f1out + ((size_t)(b * 256 + h)) * 16384;
#pragma unroll
        for (int ct = 0; ct < 2; ++ct)
#pragma unroll
            for (int pt = 0; pt < 2; ++pt) {
                int pix = pw0 + pt * 32 + l31;
                ushort_t* po = outb + (size_t)pix * 64 + ct * 32 + co_b;
#pragma unroll
                for (int q = 0; q < 4; ++q) {
                    float4v bv = *(const float4v*)(ba + ct * 32 + co_b + 8 * q);
                    short4v sv;
#pragma unroll
                    for (int m = 0; m < 4; ++m) {
                        float v = lrelu(accA[ct][pt][q * 4 + m] + bv[m]);
                        sv[m] = (short)f2bf(v);
                    }
                    *(short4v*)(po + 8 * q) = sv;
                }
            }
    }
    {   // conv3 -> fp32 NCHW + cb
        float* pb = cres + (((size_t)b * 64) << 16) + h * 256;
#pragma unroll
        for (int ct = 0; ct < 2; ++ct)
#pragma unroll
            for (int pt = 0; pt < 2; ++pt) {
                int pix = pw0 + pt * 32 + l31;
#pragma unroll
                for (int q = 0; q < 4; ++q) {
                    float4v bv = *(const float4v*)(bc + ct * 32 + co_b + 8 * q);
#pragma unroll
                    for (int m = 0; m < 4; ++m) {
                        int c = ct * 32 + co_b + 8 * q + m;
                        pb[((size_t)c << 16) + pix] = accC[ct][pt][q * 4 + m] + bv[m];
                    }
                }
            }
    }
}

// ---------------------------------------------------------------------------
// conv2: 3x3 conv 64->64, leaky, bf16 NHWC in -> bf16 NCHW out.
// ---------------------------------------------------------------------------
__global__ __launch_bounds__(256, 3) void k_conv2(const ushort_t* __restrict__ in,
                                                  const ushort_t* __restrict__ zv,
                                                  const ushort_t* __restrict__ wp,
                                                  const float* __restrict__ bias,
                                                  ushort_t* __restrict__ outp) {
    __shared__ __align__(16) ushort_t xs[3136 * 8];
    const int tid = threadIdx.x;
    const int lane = tid & 63;
    const int wv = tid >> 6;
    const unsigned bid = blockIdx.x;
    const unsigned L = (bid & 7u) * 512u + (bid >> 3);
    const int h = L & 255, b = L >> 8;
    const int l31 = lane & 31, lhi = lane >> 5;
    const int pw0 = wv * 64;

    const ushort_t* rb0 = (h > 0)   ? in + ((size_t)(b * 256 + h - 1)) * 16384 : zv;
    const ushort_t* rb1 =             in + ((size_t)(b * 256 + h)) * 16384;
    const ushort_t* rb2 = (h < 255) ? in + ((size_t)(b * 256 + h + 1)) * 16384 : zv;

    f32x16 acc[2][2];
#pragma unroll
    for (int a = 0; a < 2; ++a)
#pragma unroll
        for (int c = 0; c < 2; ++c) acc[a][c] = (f32x16)0.0f;

    for (int ch = 0; ch < 2; ++ch) {
        __syncthreads();
#pragma unroll
        for (int it = 0; it < 13; ++it) {
            int base = it * 256 + wv * 64;
            if (base < 3120) {
                int S = base + lane;
                S = S < 3120 ? S : 3119;
                int r = (S >= 2080) ? 2 : (S >= 1040 ? 1 : 0);
                int rem = S - r * 1040;
                int m = rem >> 3, sl = rem & 7;
                int sp = sl ^ (m & 7);
                int p = 2 * m + (sp >> 2), g = sp & 3;
                int ws = p - 1;
                bool edge = (unsigned)ws >= 256u;
                const ushort_t* rp = (r == 0) ? rb0 : (r == 1 ? rb1 : rb2);
                const ushort_t* src = edge ? zv : (rp + ws * 64 + ch * 32 + g * 8);
                gload_lds16(src, xs + (size_t)base * 8);
            }
        }
        asm volatile("s_waitcnt vmcnt(0)" ::: "memory");
        __syncthreads();

#pragma unroll
        for (int t = 0; t < 9; ++t) {
            const int dw = t % 3;
            const int rr = t / 3;
#pragma unroll
            for (int kc = 0; kc < 2; ++kc) {
                const ushort_t* wpf = wp + (((((t * 2 + ch) * 2 + kc) * 2) * 64 + lane) * 8);
                short8 a0 = *(const short8*)(wpf);
                short8 a1 = *(const short8*)(wpf + 512);
                const int g = kc * 2 + lhi;
#pragma unroll
                for (int pt = 0; pt < 2; ++pt) {
                    int p = pw0 + pt * 32 + l31 + dw;
                    int slot = ((p & 1) * 4 + g) ^ ((p >> 1) & 7);
                    short8 bf = *(const short8*)(xs + (((size_t)rr * 130 + (p >> 1)) * 8 + slot) * 8);
                    acc[0][pt] = __builtin_amdgcn_mfma_f32_32x32x16_bf16(a0, bf, acc[0][pt], 0, 0, 0);
                    acc[1][pt] = __builtin_amdgcn_mfma_f32_32x32x16_bf16(a1, bf, acc[1][pt], 0, 0, 0);
                }
            }
        }
    }

    const int co_b = 4 * lhi;
    // bf16 NCHW: per (c), half-wave writes 32 consecutive pix (64 B).
    ushort_t* pb = outp + (((size_t)b * 64) << 16) + h * 256;
#pragma unroll
    for (int ct = 0; ct < 2; ++ct)
#pragma unroll
        for (int pt = 0; pt < 2; ++pt) {
            int pix = pw0 + pt * 32 + l31;
#pragma unroll
            for (int q = 0; q < 4; ++q) {
                float4v bv = *(const float4v*)(bias + ct * 32 + co_b + 8 * q);
#pragma unroll
                for (int m = 0; m < 4; ++m) {
                    int c = ct * 32 + co_b + 8 * q + m;
                    float v = lrelu(acc[ct][pt][q * 4 + m] + bv[m]);
                    pb[((size_t)c << 16) + pix] = f2bf(v);
                }
            }
        }
}

// ---------------------------------------------------------------------------
// Final depthwise: out[b][c][h][w] += sum_tap ktr[b][tap][c] * f2[b][c][h'][w']
// Block = (b, c, 8-row band); f2 is bf16 NCHW. 5.4 KB LDS -> high occupancy.
// ---------------------------------------------------------------------------
__global__ __launch_bounds__(256) void k_fin(const ushort_t* __restrict__ f2,
                                             const float* __restrict__ ktr,
                                             float* __restrict__ out) {
    __shared__ __align__(16) ushort_t s[10 * 272];
    const unsigned bid = blockIdx.x;
    const unsigned L = (bid & 7u) * 4096u + (bid >> 3);  // bijective, 32768=8*4096
    const int hb = L & 31, c = (L >> 5) & 63, b = L >> 11;
    const int h0 = hb * 8;
    const int w = threadIdx.x;

    const ushort_t* f2c = f2 + (((size_t)(b * 64 + c)) << 16);
    for (int i = w; i < 320; i += 256) {
        int r = i >> 5, seg = i & 31;
        int hs = h0 - 1 + r;
        short8 v = (short8)0;
        if ((unsigned)hs < 256u) v = *(const short8*)(f2c + hs * 256 + seg * 8);
        *(short8*)(&s[r * 272 + 8 + seg * 8]) = v;
        if (seg == 0) s[r * 272 + 7] = 0;
        if (seg == 31) s[r * 272 + 264] = 0;
    }
    __syncthreads();

    float kv[9];
#pragma unroll
    for (int t9 = 0; t9 < 9; ++t9) kv[t9] = ktr[b * 576 + t9 * 64 + c];

    float lv[10], cv[10], rv[10];
#pragma unroll
    for (int r = 0; r < 10; ++r) {
        lv[r] = bf2f(s[r * 272 + 7 + w]);
        cv[r] = bf2f(s[r * 272 + 8 + w]);
        rv[r] = bf2f(s[r * 272 + 9 + w]);
    }

    float* ob = out + (((size_t)(b * 64 + c)) << 16) + h0 * 256 + w;
#pragma unroll
    for (int rr = 0; rr < 8; ++rr) {
        float dwv = 0.f;
#pragma unroll
        for (int r3 = 0; r3 < 3; ++r3) {
            dwv = fmaf(kv[r3 * 3 + 0], lv[rr + r3], dwv);
            dwv = fmaf(kv[r3 * 3 + 1], cv[rr + r3], dwv);
            dwv = fmaf(kv[r3 * 3 + 2], rv[rr + r3], dwv);
        }
        float* po = ob + rr * 256;
        *po = *po + dwv;
    }
}

// ---------------------------------------------------------------------------
extern "C" void kernel_launch(void* const* d_in, const int* in_sizes, int n_in,
                              void* d_out, int out_size, void* d_ws, size_t ws_size,
                              hipStream_t stream) {
    const float* x   = (const float*)d_in[0];
    const float* t   = (const float*)d_in[1];
    const float* tW1 = (const float*)d_in[2];
    const float* tW2 = (const float*)d_in[3];
    const float* fW1 = (const float*)d_in[4];
    const float* fb1 = (const float*)d_in[5];
    const float* fW2 = (const float*)d_in[6];
    const float* fb2 = (const float*)d_in[7];
    const float* kW1 = (const float*)d_in[8];
    const float* kW2 = (const float*)d_in[9];
    const float* cW  = (const float*)d_in[10];
    const float* cb  = (const float*)d_in[11];

    // ws: [ktr 36K @0][wp 216K @65536][zv 32K @294912]
    //     [R1 128MB @512K]  : xbf (phase 1-2), then f2 (phase 3-4)
    //     [R2 128MB @512K+128MB] : f1 (phase 2-3)
    char* ws = (char*)d_ws;
    float*    ktr  = (float*)ws;
    ushort_t* wp   = (ushort_t*)(ws + 65536);
    ushort_t* zv   = (ushort_t*)(ws + 294912);
    ushort_t* xbf  = (ushort_t*)(ws + (512u << 10));                       // R1
    ushort_t* f1bf = (ushort_t*)(ws + (512u << 10) + ((size_t)128 << 20)); // R2
    ushort_t* f2n  = xbf;  // R1 reused: xbf dead after k_conv13
    float*    out  = (float*)d_out;

    k_tiny<<<dim3(16), dim3(64), 0, stream>>>(t, tW1, tW2, kW1, kW2, ktr);
    k_zrow<<<dim3(8), dim3(256), 0, stream>>>(zv);
    k_pack<<<dim3((3 * 36864 + 255) / 256), dim3(256), 0, stream>>>(fW1, fW2, cW, wp);
    k_tr<<<dim3(4096), dim3(256), 0, stream>>>(x, xbf);

    k_conv13<<<dim3(4096), dim3(256), 0, stream>>>(
        xbf, zv, wp, wp + 2 * 36864, fb1, cb, f1bf, out);
    k_conv2<<<dim3(4096), dim3(256), 0, stream>>>(f1bf, zv, wp + 36864, fb2, f2n);
    k_fin<<<dim3(32768), dim3(256), 0, stream>>>(f2n, ktr, out);
}

// Round 8
// 631.055 us; speedup vs baseline: 1.1348x; 1.1348x over previous
//
#include <hip/hip_runtime.h>
#include <cstdint>

// B=16, C=64, H=W=256. 3x3 convs via bf16 MFMA implicit GEMM.
// Round 8: K pipelined in 4 chunks of 16 ci with double-buffered LDS
// (2 x 1632 slots x 16B = 52 KB), raw s_barrier + counted vmcnt(7)
// (never vmcnt(0) mid-loop), per-tap A-frag hoisting, setprio around MFMA.
// Swizzle: macro-row = 4 pixels x 16ci; slot sl = ((p&3)*2+g) ^ ((p>>2)&7).
using short8  = __attribute__((ext_vector_type(8))) short;
using short4v = __attribute__((ext_vector_type(4))) short;
using f32x16  = __attribute__((ext_vector_type(16))) float;
using float4v = __attribute__((ext_vector_type(4))) float;
typedef unsigned short ushort_t;

#define CHUNK_ROW 520    // 65 macro-groups x 8 slots
#define CHUNK_SLOTS 1560 // 3 rows
#define BUF_SLOTS 1632   // padded (staging stripes over-run to 1617)
#define BUF_SHORTS (BUF_SLOTS * 8)

__device__ __forceinline__ float lrelu(float x) { return x > 0.f ? x : 0.1f * x; }

__device__ __forceinline__ ushort_t f2bf(float f) {
    union { float f; unsigned u; } v; v.f = f;
    unsigned r = (v.u + 0x7FFFu + ((v.u >> 16) & 1u)) >> 16;
    return (ushort_t)r;
}
__device__ __forceinline__ float bf2f(ushort_t b) {
    union { unsigned u; float f; } v; v.u = ((unsigned)b) << 16; return v.f;
}

// async 16B global -> LDS (dest = wave-uniform base + lane*16)
__device__ __forceinline__ void gload_lds16(const ushort_t* g, ushort_t* l) {
    __builtin_amdgcn_global_load_lds(
        (const __attribute__((address_space(1))) void*)g,
        (__attribute__((address_space(3))) void*)l, 16, 0, 0);
}

// ---------------------------------------------------------------------------
// Tiny branch: ktr[b][tap][c] = leaky(kern) * sigmoid-gate (mv folded in).
// ---------------------------------------------------------------------------
__global__ void k_tiny(const float* __restrict__ t, const float* __restrict__ tW1,
                       const float* __restrict__ tW2, const float* __restrict__ kW1,
                       const float* __restrict__ kW2, float* __restrict__ ktr) {
    int b = blockIdx.x;
    int c = threadIdx.x;  // 64
    __shared__ float h1[64], g1[64];
    float ts = t[b];
    h1[c] = lrelu(ts * tW1[c]);
    g1[c] = lrelu(ts * kW1[c]);
    __syncthreads();
    float s = 0.f;
    for (int j = 0; j < 64; ++j) s = fmaf(tW2[c * 64 + j], h1[j], s);
    float mvv = 1.f / (1.f + expf(-s));
    for (int q = 0; q < 9; ++q) {
        float s2 = 0.f;
        for (int j = 0; j < 64; ++j) s2 = fmaf(kW2[(c * 9 + q) * 64 + j], g1[j], s2);
        ktr[b * 576 + q * 64 + c] = lrelu(s2) * mvv;
    }
}

// ---------------------------------------------------------------------------
// Zero row buffer (edge-redirect source for staging).
// ---------------------------------------------------------------------------
__global__ void k_zrow(ushort_t* __restrict__ z) {
    int i = blockIdx.x * 256 + threadIdx.x;  // 2048 threads, 16384 shorts
    *(short8*)(z + (size_t)i * 8) = (short8)0;
}

// ---------------------------------------------------------------------------
// Pack three 64x64x3x3 weight tensors into MFMA A-fragment order (bf16).
// flat = ((t*4 + chunk)*2 + ct)*512 + lane*8 + j
//   = W[co = ct*32 + (lane&31)][ci = chunk*16 + (lane>>5)*8 + j], tap t
// (identical layout to prior rounds: chunk == ch*2+kc)
// ---------------------------------------------------------------------------
__global__ void k_pack(const float* __restrict__ w1, const float* __restrict__ w2,
                       const float* __restrict__ w3, ushort_t* __restrict__ wp) {
    int idx = blockIdx.x * 256 + threadIdx.x;
    if (idx >= 3 * 36864) return;
    int conv = idx / 36864, r = idx % 36864;
    const float* W = conv == 0 ? w1 : (conv == 1 ? w2 : w3);
    int j = r & 7, lane = (r >> 3) & 63, ct = (r >> 9) & 1, chunk = (r >> 10) & 3,
        t = r >> 12;
    int co = ct * 32 + (lane & 31);
    int ci = chunk * 16 + (lane >> 5) * 8 + j;
    wp[idx] = f2bf(W[(co * 64 + ci) * 9 + t]);
}

// ---------------------------------------------------------------------------
// Transpose x: fp32 NCHW -> bf16 NHWC (width-256 rows). Block = (b,h).
// ---------------------------------------------------------------------------
__global__ __launch_bounds__(256) void k_tr(const float* __restrict__ x,
                                            ushort_t* __restrict__ xbf) {
    int bid = blockIdx.x;
    int h = bid & 255, b = bid >> 8;
    int t = threadIdx.x;
    for (int it = 0; it < 8; ++it) {
        int idx = t + it * 256;  // (w, g)
        int g = idx & 7, w = idx >> 3;
        const float* src = x + (((size_t)(b * 64 + g * 8) * 256 + h) * 256 + w);
        short8 v;
#pragma unroll
        for (int j = 0; j < 8; ++j) v[j] = (short)f2bf(src[(size_t)j * 65536]);
        *(short8*)(xbf + (((size_t)(b * 256 + h) * 256 + w) * 64 + g * 8)) = v;
    }
}

// ---------------------------------------------------------------------------
// Per-wave staging of one 16-ci chunk (7 x global_load_lds16, slots
// [wv*390, wv*390+448) with source clamped at 1559; dup writes land in pad).
// Inverse swizzle baked into per-lane source address.
// ---------------------------------------------------------------------------
#define STAGE_CHUNK(chunk, bufbase)                                              \
    {                                                                            \
        _Pragma("unroll")                                                        \
        for (int i_ = 0; i_ < 7; ++i_) {                                         \
            int base_ = wv * 390 + i_ * 64;                                      \
            int S_ = base_ + lane;                                               \
            S_ = S_ < CHUNK_SLOTS ? S_ : CHUNK_SLOTS - 1;                        \
            int row_ = (S_ >= 2 * CHUNK_ROW) ? 2 : (S_ >= CHUNK_ROW ? 1 : 0);    \
            int rem_ = S_ - row_ * CHUNK_ROW;                                    \
            int mg_ = rem_ >> 3, sl_ = rem_ & 7;                                 \
            int sp_ = sl_ ^ (mg_ & 7);                                           \
            int p_ = mg_ * 4 + (sp_ >> 1), g_ = sp_ & 1;                         \
            int wsx_ = p_ - 1;                                                   \
            bool edge_ = (unsigned)wsx_ >= 256u;                                 \
            const ushort_t* rp_ = (row_ == 0) ? rb0 : (row_ == 1 ? rb1 : rb2);   \
            const ushort_t* src_ =                                               \
                edge_ ? zv : (rp_ + wsx_ * 64 + (chunk)*16 + g_ * 8);            \
            gload_lds16(src_, xs + (bufbase) + (size_t)base_ * 8);               \
        }                                                                        \
    }

#define VMCNT(n) asm volatile("s_waitcnt vmcnt(" #n ")" ::: "memory")
#define RBAR() __builtin_amdgcn_s_barrier()

// ---------------------------------------------------------------------------
// Merged conv1+conv3 (pipelined). accA: fW1+leaky -> f1 bf16 NHWC.
// accC: cW + cb -> fp32 NCHW (d_out).
// ---------------------------------------------------------------------------
__global__ __launch_bounds__(256, 2) void k_conv13(
    const ushort_t* __restrict__ in, const ushort_t* __restrict__ zv,
    const ushort_t* __restrict__ wpa, const ushort_t* __restrict__ wpc,
    const float* __restrict__ ba, const float* __restrict__ bc,
    ushort_t* __restrict__ f1out, float* __restrict__ cres) {
    __shared__ __align__(16) ushort_t xs[2 * BUF_SHORTS];  // 52224 B
    const int tid = threadIdx.x;
    const int lane = tid & 63;
    const int wv = tid >> 6;
    const unsigned bid = blockIdx.x;
    const unsigned L = (bid & 7u) * 512u + (bid >> 3);
    const int h = L & 255, b = L >> 8;
    const int l31 = lane & 31, lhi = lane >> 5;
    const int pw0 = wv * 64;

    const ushort_t* rb0 = (h > 0)   ? in + ((size_t)(b * 256 + h - 1)) * 16384 : zv;
    const ushort_t* rb1 =             in + ((size_t)(b * 256 + h)) * 16384;
    const ushort_t* rb2 = (h < 255) ? in + ((size_t)(b * 256 + h + 1)) * 16384 : zv;

    f32x16 accA[2][2], accC[2][2];
#pragma unroll
    for (int a = 0; a < 2; ++a)
#pragma unroll
        for (int c = 0; c < 2; ++c) { accA[a][c] = (f32x16)0.0f; accC[a][c] = (f32x16)0.0f; }

#define COMPUTE13(chunk, bufbase)                                                   \
    {                                                                               \
        __builtin_amdgcn_s_setprio(1);                                              \
        _Pragma("unroll")                                                           \
        for (int t_ = 0; t_ < 9; ++t_) {                                            \
            const int dwx_ = t_ % 3, rr_ = t_ / 3;                                  \
            const int off_ = ((t_ * 4 + (chunk)) * 2) * 512 + lane * 8;             \
            short8 a0 = *(const short8*)(wpa + off_);                               \
            short8 a1 = *(const short8*)(wpa + off_ + 512);                         \
            short8 c0 = *(const short8*)(wpc + off_);                               \
            short8 c1 = *(const short8*)(wpc + off_ + 512);                         \
            _Pragma("unroll")                                                       \
            for (int pt_ = 0; pt_ < 2; ++pt_) {                                     \
                int p_ = pw0 + pt_ * 32 + l31 + dwx_;                               \
                int mg_ = p_ >> 2;                                                  \
                int sl_ = ((p_ & 3) * 2 + lhi) ^ (mg_ & 7);                         \
                short8 bf = *(const short8*)(                                       \
                    xs + (bufbase) + (size_t)(rr_ * CHUNK_ROW + mg_ * 8 + sl_) * 8);\
                accA[0][pt_] = __builtin_amdgcn_mfma_f32_32x32x16_bf16(a0, bf, accA[0][pt_], 0, 0, 0); \
                accA[1][pt_] = __builtin_amdgcn_mfma_f32_32x32x16_bf16(a1, bf, accA[1][pt_], 0, 0, 0); \
                accC[0][pt_] = __builtin_amdgcn_mfma_f32_32x32x16_bf16(c0, bf, accC[0][pt_], 0, 0, 0); \
                accC[1][pt_] = __builtin_amdgcn_mfma_f32_32x32x16_bf16(c1, bf, accC[1][pt_], 0, 0, 0); \
            }                                                                       \
        }                                                                           \
        __builtin_amdgcn_s_setprio(0);                                              \
    }

    STAGE_CHUNK(0, 0);
    STAGE_CHUNK(1, BUF_SHORTS);
    VMCNT(7);   // chunk0 resident (my 7 oldest of 14)
    RBAR();
    COMPUTE13(0, 0);
    RBAR();                       // all waves done reading buf0
    STAGE_CHUNK(2, 0);
    VMCNT(7);                     // chunk1 resident
    RBAR();
    COMPUTE13(1, BUF_SHORTS);
    RBAR();
    STAGE_CHUNK(3, BUF_SHORTS);
    VMCNT(7);                     // chunk2 resident
    RBAR();
    COMPUTE13(2, 0);
    RBAR();
    VMCNT(0);                     // chunk3 resident (epilogue drain)
    RBAR();
    COMPUTE13(3, BUF_SHORTS);

    // Epilogues. D layout: col(pix)=lane&31, row(co)=(reg&3)+8*(reg>>2)+4*(lane>>5)
    const int co_b = 4 * lhi;
    {   // conv1 -> bf16 NHWC + leaky
        ushort_t* outb = f1out + ((size_t)(b * 256 + h)) * 16384;
#pragma unroll
        for (int ct = 0; ct < 2; ++ct)
#pragma unroll
            for (int pt = 0; pt < 2; ++pt) {
                int pix = pw0 + pt * 32 + l31;
                ushort_t* po = outb + (size_t)pix * 64 + ct * 32 + co_b;
#pragma unroll
                for (int q = 0; q < 4; ++q) {
                    float4v bv = *(const float4v*)(ba + ct * 32 + co_b + 8 * q);
                    short4v sv;
#pragma unroll
                    for (int m = 0; m < 4; ++m) {
                        float v = lrelu(accA[ct][pt][q * 4 + m] + bv[m]);
                        sv[m] = (short)f2bf(v);
                    }
                    *(short4v*)(po + 8 * q) = sv;
                }
            }
    }
    {   // conv3 -> fp32 NCHW + cb
        float* pb = cres + (((size_t)b * 64) << 16) + h * 256;
#pragma unroll
        for (int ct = 0; ct < 2; ++ct)
#pragma unroll
            for (int pt = 0; pt < 2; ++pt) {
                int pix = pw0 + pt * 32 + l31;
#pragma unroll
                for (int q = 0; q < 4; ++q) {
                    float4v bv = *(const float4v*)(bc + ct * 32 + co_b + 8 * q);
#pragma unroll
                    for (int m = 0; m < 4; ++m) {
                        int c = ct * 32 + co_b + 8 * q + m;
                        pb[((size_t)c << 16) + pix] = accC[ct][pt][q * 4 + m] + bv[m];
                    }
                }
            }
    }
#undef COMPUTE13
}

// ---------------------------------------------------------------------------
// conv2 (pipelined): bf16 NHWC in -> leaky -> bf16 NCHW out.
// ---------------------------------------------------------------------------
__global__ __launch_bounds__(256, 3) void k_conv2(const ushort_t* __restrict__ in,
                                                  const ushort_t* __restrict__ zv,
                                                  const ushort_t* __restrict__ wp,
                                                  const float* __restrict__ bias,
                                                  ushort_t* __restrict__ outp) {
    __shared__ __align__(16) ushort_t xs[2 * BUF_SHORTS];
    const int tid = threadIdx.x;
    const int lane = tid & 63;
    const int wv = tid >> 6;
    const unsigned bid = blockIdx.x;
    const unsigned L = (bid & 7u) * 512u + (bid >> 3);
    const int h = L & 255, b = L >> 8;
    const int l31 = lane & 31, lhi = lane >> 5;
    const int pw0 = wv * 64;

    const ushort_t* rb0 = (h > 0)   ? in + ((size_t)(b * 256 + h - 1)) * 16384 : zv;
    const ushort_t* rb1 =             in + ((size_t)(b * 256 + h)) * 16384;
    const ushort_t* rb2 = (h < 255) ? in + ((size_t)(b * 256 + h + 1)) * 16384 : zv;

    f32x16 acc[2][2];
#pragma unroll
    for (int a = 0; a < 2; ++a)
#pragma unroll
        for (int c = 0; c < 2; ++c) acc[a][c] = (f32x16)0.0f;

#define COMPUTE2(chunk, bufbase)                                                    \
    {                                                                               \
        __builtin_amdgcn_s_setprio(1);                                              \
        _Pragma("unroll")                                                           \
        for (int t_ = 0; t_ < 9; ++t_) {                                            \
            const int dwx_ = t_ % 3, rr_ = t_ / 3;                                  \
            const int off_ = ((t_ * 4 + (chunk)) * 2) * 512 + lane * 8;             \
            short8 a0 = *(const short8*)(wp + off_);                                \
            short8 a1 = *(const short8*)(wp + off_ + 512);                          \
            _Pragma("unroll")                                                       \
            for (int pt_ = 0; pt_ < 2; ++pt_) {                                     \
                int p_ = pw0 + pt_ * 32 + l31 + dwx_;                               \
                int mg_ = p_ >> 2;                                                  \
                int sl_ = ((p_ & 3) * 2 + lhi) ^ (mg_ & 7);                         \
                short8 bf = *(const short8*)(                                       \
                    xs + (bufbase) + (size_t)(rr_ * CHUNK_ROW + mg_ * 8 + sl_) * 8);\
                acc[0][pt_] = __builtin_amdgcn_mfma_f32_32x32x16_bf16(a0, bf, acc[0][pt_], 0, 0, 0); \
                acc[1][pt_] = __builtin_amdgcn_mfma_f32_32x32x16_bf16(a1, bf, acc[1][pt_], 0, 0, 0); \
            }                                                                       \
        }                                                                           \
        __builtin_amdgcn_s_setprio(0);                                              \
    }

    STAGE_CHUNK(0, 0);
    STAGE_CHUNK(1, BUF_SHORTS);
    VMCNT(7);
    RBAR();
    COMPUTE2(0, 0);
    RBAR();
    STAGE_CHUNK(2, 0);
    VMCNT(7);
    RBAR();
    COMPUTE2(1, BUF_SHORTS);
    RBAR();
    STAGE_CHUNK(3, BUF_SHORTS);
    VMCNT(7);
    RBAR();
    COMPUTE2(2, 0);
    RBAR();
    VMCNT(0);
    RBAR();
    COMPUTE2(3, BUF_SHORTS);

    const int co_b = 4 * lhi;
    // bf16 NCHW: per (c), half-wave writes 32 consecutive pix (64 B).
    ushort_t* pb = outp + (((size_t)b * 64) << 16) + h * 256;
#pragma unroll
    for (int ct = 0; ct < 2; ++ct)
#pragma unroll
        for (int pt = 0; pt < 2; ++pt) {
            int pix = pw0 + pt * 32 + l31;
#pragma unroll
            for (int q = 0; q < 4; ++q) {
                float4v bv = *(const float4v*)(bias + ct * 32 + co_b + 8 * q);
#pragma unroll
                for (int m = 0; m < 4; ++m) {
                    int c = ct * 32 + co_b + 8 * q + m;
                    float v = lrelu(acc[ct][pt][q * 4 + m] + bv[m]);
                    pb[((size_t)c << 16) + pix] = f2bf(v);
                }
            }
        }
#undef COMPUTE2
}

// ---------------------------------------------------------------------------
// Final depthwise: out[b][c][h][w] += sum_tap ktr[b][tap][c] * f2[b][c][h'][w']
// Block = (b, c, 8-row band); f2 is bf16 NCHW.
// ---------------------------------------------------------------------------
__global__ __launch_bounds__(256) void k_fin(const ushort_t* __restrict__ f2,
                                             const float* __restrict__ ktr,
                                             float* __restrict__ out) {
    __shared__ __align__(16) ushort_t s[10 * 272];
    const unsigned bid = blockIdx.x;
    const unsigned L = (bid & 7u) * 4096u + (bid >> 3);  // bijective, 32768=8*4096
    const int hb = L & 31, c = (L >> 5) & 63, b = L >> 11;
    const int h0 = hb * 8;
    const int w = threadIdx.x;

    const ushort_t* f2c = f2 + (((size_t)(b * 64 + c)) << 16);
    for (int i = w; i < 320; i += 256) {
        int r = i >> 5, seg = i & 31;
        int hs = h0 - 1 + r;
        short8 v = (short8)0;
        if ((unsigned)hs < 256u) v = *(const short8*)(f2c + hs * 256 + seg * 8);
        *(short8*)(&s[r * 272 + 8 + seg * 8]) = v;
        if (seg == 0) s[r * 272 + 7] = 0;
        if (seg == 31) s[r * 272 + 264] = 0;
    }
    __syncthreads();

    float kv[9];
#pragma unroll
    for (int t9 = 0; t9 < 9; ++t9) kv[t9] = ktr[b * 576 + t9 * 64 + c];

    float lv[10], cv[10], rv[10];
#pragma unroll
    for (int r = 0; r < 10; ++r) {
        lv[r] = bf2f(s[r * 272 + 7 + w]);
        cv[r] = bf2f(s[r * 272 + 8 + w]);
        rv[r] = bf2f(s[r * 272 + 9 + w]);
    }

    float* ob = out + (((size_t)(b * 64 + c)) << 16) + h0 * 256 + w;
#pragma unroll
    for (int rr = 0; rr < 8; ++rr) {
        float dwv = 0.f;
#pragma unroll
        for (int r3 = 0; r3 < 3; ++r3) {
            dwv = fmaf(kv[r3 * 3 + 0], lv[rr + r3], dwv);
            dwv = fmaf(kv[r3 * 3 + 1], cv[rr + r3], dwv);
            dwv = fmaf(kv[r3 * 3 + 2], rv[rr + r3], dwv);
        }
        float* po = ob + rr * 256;
        *po = *po + dwv;
    }
}

// ---------------------------------------------------------------------------
extern "C" void kernel_launch(void* const* d_in, const int* in_sizes, int n_in,
                              void* d_out, int out_size, void* d_ws, size_t ws_size,
                              hipStream_t stream) {
    const float* x   = (const float*)d_in[0];
    const float* t   = (const float*)d_in[1];
    const float* tW1 = (const float*)d_in[2];
    const float* tW2 = (const float*)d_in[3];
    const float* fW1 = (const float*)d_in[4];
    const float* fb1 = (const float*)d_in[5];
    const float* fW2 = (const float*)d_in[6];
    const float* fb2 = (const float*)d_in[7];
    const float* kW1 = (const float*)d_in[8];
    const float* kW2 = (const float*)d_in[9];
    const float* cW  = (const float*)d_in[10];
    const float* cb  = (const float*)d_in[11];

    // ws: [ktr 36K @0][wp 216K @65536][zv 32K @294912]
    //     [R1 128MB @512K]  : xbf (phase 1-2), then f2 (phase 3-4)
    //     [R2 128MB @512K+128MB] : f1 (phase 2-3)
    char* ws = (char*)d_ws;
    float*    ktr  = (float*)ws;
    ushort_t* wp   = (ushort_t*)(ws + 65536);
    ushort_t* zv   = (ushort_t*)(ws + 294912);
    ushort_t* xbf  = (ushort_t*)(ws + (512u << 10));                       // R1
    ushort_t* f1bf = (ushort_t*)(ws + (512u << 10) + ((size_t)128 << 20)); // R2
    ushort_t* f2n  = xbf;  // R1 reused: xbf dead after k_conv13
    float*    out  = (float*)d_out;

    k_tiny<<<dim3(16), dim3(64), 0, stream>>>(t, tW1, tW2, kW1, kW2, ktr);
    k_zrow<<<dim3(8), dim3(256), 0, stream>>>(zv);
    k_pack<<<dim3((3 * 36864 + 255) / 256), dim3(256), 0, stream>>>(fW1, fW2, cW, wp);
    k_tr<<<dim3(4096), dim3(256), 0, stream>>>(x, xbf);

    k_conv13<<<dim3(4096), dim3(256), 0, stream>>>(
        xbf, zv, wp, wp + 2 * 36864, fb1, cb, f1bf, out);
    k_conv2<<<dim3(4096), dim3(256), 0, stream>>>(f1bf, zv, wp + 36864, fb2, f2n);
    k_fin<<<dim3(32768), dim3(256), 0, stream>>>(f2n, ktr, out);
}

// Round 9
// 629.050 us; speedup vs baseline: 1.1384x; 1.0032x over previous
//
#include <hip/hip_runtime.h>
#include <cstdint>

// B=16, C=64, H=W=256. 3x3 convs via bf16 MFMA implicit GEMM.
// Round 9: fix vmcnt FIFO false-dependency — tap-0 A-frag (weight) loads are
// hoisted BEFORE the next chunk's STAGE issue (kept older via asm memory
// barrier), counted waits corrected (retire exactly the previous stage's 7),
// and the tap loop does explicit depth-1 rolling A-frag prefetch.
using short8  = __attribute__((ext_vector_type(8))) short;
using short4v = __attribute__((ext_vector_type(4))) short;
using f32x16  = __attribute__((ext_vector_type(16))) float;
using float4v = __attribute__((ext_vector_type(4))) float;
typedef unsigned short ushort_t;

#define CHUNK_ROW 520    // 65 macro-groups x 8 slots
#define CHUNK_SLOTS 1560 // 3 rows
#define BUF_SLOTS 1632   // padded (staging stripes over-run to 1617)
#define BUF_SHORTS (BUF_SLOTS * 8)

__device__ __forceinline__ float lrelu(float x) { return x > 0.f ? x : 0.1f * x; }

__device__ __forceinline__ ushort_t f2bf(float f) {
    union { float f; unsigned u; } v; v.f = f;
    unsigned r = (v.u + 0x7FFFu + ((v.u >> 16) & 1u)) >> 16;
    return (ushort_t)r;
}
__device__ __forceinline__ float bf2f(ushort_t b) {
    union { unsigned u; float f; } v; v.u = ((unsigned)b) << 16; return v.f;
}

// async 16B global -> LDS (dest = wave-uniform base + lane*16)
__device__ __forceinline__ void gload_lds16(const ushort_t* g, ushort_t* l) {
    __builtin_amdgcn_global_load_lds(
        (const __attribute__((address_space(1))) void*)g,
        (__attribute__((address_space(3))) void*)l, 16, 0, 0);
}

// ---------------------------------------------------------------------------
// Tiny branch: ktr[b][tap][c] = leaky(kern) * sigmoid-gate (mv folded in).
// ---------------------------------------------------------------------------
__global__ void k_tiny(const float* __restrict__ t, const float* __restrict__ tW1,
                       const float* __restrict__ tW2, const float* __restrict__ kW1,
                       const float* __restrict__ kW2, float* __restrict__ ktr) {
    int b = blockIdx.x;
    int c = threadIdx.x;  // 64
    __shared__ float h1[64], g1[64];
    float ts = t[b];
    h1[c] = lrelu(ts * tW1[c]);
    g1[c] = lrelu(ts * kW1[c]);
    __syncthreads();
    float s = 0.f;
    for (int j = 0; j < 64; ++j) s = fmaf(tW2[c * 64 + j], h1[j], s);
    float mvv = 1.f / (1.f + expf(-s));
    for (int q = 0; q < 9; ++q) {
        float s2 = 0.f;
        for (int j = 0; j < 64; ++j) s2 = fmaf(kW2[(c * 9 + q) * 64 + j], g1[j], s2);
        ktr[b * 576 + q * 64 + c] = lrelu(s2) * mvv;
    }
}

// ---------------------------------------------------------------------------
// Zero row buffer (edge-redirect source for staging).
// ---------------------------------------------------------------------------
__global__ void k_zrow(ushort_t* __restrict__ z) {
    int i = blockIdx.x * 256 + threadIdx.x;  // 2048 threads, 16384 shorts
    *(short8*)(z + (size_t)i * 8) = (short8)0;
}

// ---------------------------------------------------------------------------
// Pack three 64x64x3x3 weight tensors into MFMA A-fragment order (bf16).
// flat = ((t*4 + chunk)*2 + ct)*512 + lane*8 + j
//   = W[co = ct*32 + (lane&31)][ci = chunk*16 + (lane>>5)*8 + j], tap t
// ---------------------------------------------------------------------------
__global__ void k_pack(const float* __restrict__ w1, const float* __restrict__ w2,
                       const float* __restrict__ w3, ushort_t* __restrict__ wp) {
    int idx = blockIdx.x * 256 + threadIdx.x;
    if (idx >= 3 * 36864) return;
    int conv = idx / 36864, r = idx % 36864;
    const float* W = conv == 0 ? w1 : (conv == 1 ? w2 : w3);
    int j = r & 7, lane = (r >> 3) & 63, ct = (r >> 9) & 1, chunk = (r >> 10) & 3,
        t = r >> 12;
    int co = ct * 32 + (lane & 31);
    int ci = chunk * 16 + (lane >> 5) * 8 + j;
    wp[idx] = f2bf(W[(co * 64 + ci) * 9 + t]);
}

// ---------------------------------------------------------------------------
// Transpose x: fp32 NCHW -> bf16 NHWC (width-256 rows). Block = (b,h).
// ---------------------------------------------------------------------------
__global__ __launch_bounds__(256) void k_tr(const float* __restrict__ x,
                                            ushort_t* __restrict__ xbf) {
    int bid = blockIdx.x;
    int h = bid & 255, b = bid >> 8;
    int t = threadIdx.x;
    for (int it = 0; it < 8; ++it) {
        int idx = t + it * 256;  // (w, g)
        int g = idx & 7, w = idx >> 3;
        const float* src = x + (((size_t)(b * 64 + g * 8) * 256 + h) * 256 + w);
        short8 v;
#pragma unroll
        for (int j = 0; j < 8; ++j) v[j] = (short)f2bf(src[(size_t)j * 65536]);
        *(short8*)(xbf + (((size_t)(b * 256 + h) * 256 + w) * 64 + g * 8)) = v;
    }
}

// ---------------------------------------------------------------------------
// Per-wave staging of one 16-ci chunk (7 x global_load_lds16).
// Inverse swizzle baked into per-lane source address.
// ---------------------------------------------------------------------------
#define STAGE_CHUNK(chunk, bufbase)                                              \
    {                                                                            \
        _Pragma("unroll")                                                        \
        for (int i_ = 0; i_ < 7; ++i_) {                                         \
            int base_ = wv * 390 + i_ * 64;                                      \
            int S_ = base_ + lane;                                               \
            S_ = S_ < CHUNK_SLOTS ? S_ : CHUNK_SLOTS - 1;                        \
            int row_ = (S_ >= 2 * CHUNK_ROW) ? 2 : (S_ >= CHUNK_ROW ? 1 : 0);    \
            int rem_ = S_ - row_ * CHUNK_ROW;                                    \
            int mg_ = rem_ >> 3, sl_ = rem_ & 7;                                 \
            int sp_ = sl_ ^ (mg_ & 7);                                           \
            int p_ = mg_ * 4 + (sp_ >> 1), g_ = sp_ & 1;                         \
            int wsx_ = p_ - 1;                                                   \
            bool edge_ = (unsigned)wsx_ >= 256u;                                 \
            const ushort_t* rp_ = (row_ == 0) ? rb0 : (row_ == 1 ? rb1 : rb2);   \
            const ushort_t* src_ =                                               \
                edge_ ? zv : (rp_ + wsx_ * 64 + (chunk)*16 + g_ * 8);            \
            gload_lds16(src_, xs + (bufbase) + (size_t)base_ * 8);               \
        }                                                                        \
    }

#define VMCNT(n) asm volatile("s_waitcnt vmcnt(" #n ")" ::: "memory")
#define RBAR() __builtin_amdgcn_s_barrier()
#define PIN() asm volatile("" ::: "memory")

// ---------------------------------------------------------------------------
// A-frag preload + rolling-prefetch compute for the merged conv1+conv3.
// ---------------------------------------------------------------------------
__device__ __forceinline__ void apre13(const ushort_t* __restrict__ wpa,
                                       const ushort_t* __restrict__ wpc,
                                       int chunk, int lane, short8& a0, short8& a1,
                                       short8& c0, short8& c1) {
    const int off = ((0 * 4 + chunk) * 2) * 512 + lane * 8;
    a0 = *(const short8*)(wpa + off);
    a1 = *(const short8*)(wpa + off + 512);
    c0 = *(const short8*)(wpc + off);
    c1 = *(const short8*)(wpc + off + 512);
}

__device__ __forceinline__ void compute13(
    const ushort_t* __restrict__ wpa, const ushort_t* __restrict__ wpc,
    const ushort_t* xs, int bufbase, int chunk, int lane, int pw0, int l31, int lhi,
    short8 ca0, short8 ca1, short8 cc0, short8 cc1,
    f32x16 (&accA)[2][2], f32x16 (&accC)[2][2]) {
    __builtin_amdgcn_s_setprio(1);
#pragma unroll
    for (int t = 0; t < 9; ++t) {
        short8 na0, na1, nc0, nc1;
        if (t < 8) {
            const int off = (((t + 1) * 4 + chunk) * 2) * 512 + lane * 8;
            na0 = *(const short8*)(wpa + off);
            na1 = *(const short8*)(wpa + off + 512);
            nc0 = *(const short8*)(wpc + off);
            nc1 = *(const short8*)(wpc + off + 512);
        }
        const int dwx = t % 3, rr = t / 3;
#pragma unroll
        for (int pt = 0; pt < 2; ++pt) {
            int p = pw0 + pt * 32 + l31 + dwx;
            int mg = p >> 2;
            int sl = ((p & 3) * 2 + lhi) ^ (mg & 7);
            short8 bf = *(const short8*)(xs + bufbase +
                                         (size_t)(rr * CHUNK_ROW + mg * 8 + sl) * 8);
            accA[0][pt] = __builtin_amdgcn_mfma_f32_32x32x16_bf16(ca0, bf, accA[0][pt], 0, 0, 0);
            accA[1][pt] = __builtin_amdgcn_mfma_f32_32x32x16_bf16(ca1, bf, accA[1][pt], 0, 0, 0);
            accC[0][pt] = __builtin_amdgcn_mfma_f32_32x32x16_bf16(cc0, bf, accC[0][pt], 0, 0, 0);
            accC[1][pt] = __builtin_amdgcn_mfma_f32_32x32x16_bf16(cc1, bf, accC[1][pt], 0, 0, 0);
        }
        if (t < 8) { ca0 = na0; ca1 = na1; cc0 = nc0; cc1 = nc1; }
    }
    __builtin_amdgcn_s_setprio(0);
}

// ---------------------------------------------------------------------------
// Merged conv1+conv3 (pipelined, fixed vmcnt ordering).
// ---------------------------------------------------------------------------
__global__ __launch_bounds__(256, 2) void k_conv13(
    const ushort_t* __restrict__ in, const ushort_t* __restrict__ zv,
    const ushort_t* __restrict__ wpa, const ushort_t* __restrict__ wpc,
    const float* __restrict__ ba, const float* __restrict__ bc,
    ushort_t* __restrict__ f1out, float* __restrict__ cres) {
    __shared__ __align__(16) ushort_t xs[2 * BUF_SHORTS];  // 52224 B
    const int tid = threadIdx.x;
    const int lane = tid & 63;
    const int wv = tid >> 6;
    const unsigned bid = blockIdx.x;
    const unsigned L = (bid & 7u) * 512u + (bid >> 3);
    const int h = L & 255, b = L >> 8;
    const int l31 = lane & 31, lhi = lane >> 5;
    const int pw0 = wv * 64;

    const ushort_t* rb0 = (h > 0)   ? in + ((size_t)(b * 256 + h - 1)) * 16384 : zv;
    const ushort_t* rb1 =             in + ((size_t)(b * 256 + h)) * 16384;
    const ushort_t* rb2 = (h < 255) ? in + ((size_t)(b * 256 + h + 1)) * 16384 : zv;

    f32x16 accA[2][2], accC[2][2];
#pragma unroll
    for (int a = 0; a < 2; ++a)
#pragma unroll
        for (int c = 0; c < 2; ++c) { accA[a][c] = (f32x16)0.0f; accC[a][c] = (f32x16)0.0f; }

    short8 pa0, pa1, pc0, pc1;
    // Prologue: A(chunk0) older than all stage loads.
    apre13(wpa, wpc, 0, lane, pa0, pa1, pc0, pc1);
    PIN();
    STAGE_CHUNK(0, 0);
    STAGE_CHUNK(1, BUF_SHORTS);
    VMCNT(7);   // retire A(4)+stage0(7); leave stage1(7)
    RBAR();
    compute13(wpa, wpc, xs, 0, 0, lane, pw0, l31, lhi, pa0, pa1, pc0, pc1, accA, accC);
    apre13(wpa, wpc, 1, lane, pa0, pa1, pc0, pc1);
    PIN();
    RBAR();                       // all waves done reading buf0
    STAGE_CHUNK(2, 0);
    VMCNT(11);                    // retire stage1(7); leave A(4)+stage2(7)
    RBAR();
    compute13(wpa, wpc, xs, BUF_SHORTS, 1, lane, pw0, l31, lhi, pa0, pa1, pc0, pc1, accA, accC);
    apre13(wpa, wpc, 2, lane, pa0, pa1, pc0, pc1);
    PIN();
    RBAR();
    STAGE_CHUNK(3, BUF_SHORTS);
    VMCNT(11);                    // retire stage2(7); leave A(4)+stage3(7)
    RBAR();
    compute13(wpa, wpc, xs, 0, 2, lane, pw0, l31, lhi, pa0, pa1, pc0, pc1, accA, accC);
    apre13(wpa, wpc, 3, lane, pa0, pa1, pc0, pc1);
    PIN();
    RBAR();
    VMCNT(4);                     // retire stage3(7); leave A(4)
    RBAR();
    compute13(wpa, wpc, xs, BUF_SHORTS, 3, lane, pw0, l31, lhi, pa0, pa1, pc0, pc1, accA, accC);

    // Epilogues. D layout: col(pix)=lane&31, row(co)=(reg&3)+8*(reg>>2)+4*(lane>>5)
    const int co_b = 4 * lhi;
    {   // conv1 -> bf16 NHWC + leaky
        ushort_t* outb = f1out + ((size_t)(b * 256 + h)) * 16384;
#pragma unroll
        for (int ct = 0; ct < 2; ++ct)
#pragma unroll
            for (int pt = 0; pt < 2; ++pt) {
                int pix = pw0 + pt * 32 + l31;
                ushort_t* po = outb + (size_t)pix * 64 + ct * 32 + co_b;
#pragma unroll
                for (int q = 0; q < 4; ++q) {
                    float4v bv = *(const float4v*)(ba + ct * 32 + co_b + 8 * q);
                    short4v sv;
#pragma unroll
                    for (int m = 0; m < 4; ++m) {
                        float v = lrelu(accA[ct][pt][q * 4 + m] + bv[m]);
                        sv[m] = (short)f2bf(v);
                    }
                    *(short4v*)(po + 8 * q) = sv;
                }
            }
    }
    {   // conv3 -> fp32 NCHW + cb
        float* pb = cres + (((size_t)b * 64) << 16) + h * 256;
#pragma unroll
        for (int ct = 0; ct < 2; ++ct)
#pragma unroll
            for (int pt = 0; pt < 2; ++pt) {
                int pix = pw0 + pt * 32 + l31;
#pragma unroll
                for (int q = 0; q < 4; ++q) {
                    float4v bv = *(const float4v*)(bc + ct * 32 + co_b + 8 * q);
#pragma unroll
                    for (int m = 0; m < 4; ++m) {
                        int c = ct * 32 + co_b + 8 * q + m;
                        pb[((size_t)c << 16) + pix] = accC[ct][pt][q * 4 + m] + bv[m];
                    }
                }
            }
    }
}

// ---------------------------------------------------------------------------
// conv2 (pipelined, fixed vmcnt ordering): bf16 NHWC in -> leaky -> bf16 NCHW.
// ---------------------------------------------------------------------------
__device__ __forceinline__ void apre2(const ushort_t* __restrict__ wp, int chunk,
                                      int lane, short8& a0, short8& a1) {
    const int off = ((0 * 4 + chunk) * 2) * 512 + lane * 8;
    a0 = *(const short8*)(wp + off);
    a1 = *(const short8*)(wp + off + 512);
}

__device__ __forceinline__ void compute2(
    const ushort_t* __restrict__ wp, const ushort_t* xs, int bufbase, int chunk,
    int lane, int pw0, int l31, int lhi, short8 ca0, short8 ca1,
    f32x16 (&acc)[2][2]) {
    __builtin_amdgcn_s_setprio(1);
#pragma unroll
    for (int t = 0; t < 9; ++t) {
        short8 na0, na1;
        if (t < 8) {
            const int off = (((t + 1) * 4 + chunk) * 2) * 512 + lane * 8;
            na0 = *(const short8*)(wp + off);
            na1 = *(const short8*)(wp + off + 512);
        }
        const int dwx = t % 3, rr = t / 3;
#pragma unroll
        for (int pt = 0; pt < 2; ++pt) {
            int p = pw0 + pt * 32 + l31 + dwx;
            int mg = p >> 2;
            int sl = ((p & 3) * 2 + lhi) ^ (mg & 7);
            short8 bf = *(const short8*)(xs + bufbase +
                                         (size_t)(rr * CHUNK_ROW + mg * 8 + sl) * 8);
            acc[0][pt] = __builtin_amdgcn_mfma_f32_32x32x16_bf16(ca0, bf, acc[0][pt], 0, 0, 0);
            acc[1][pt] = __builtin_amdgcn_mfma_f32_32x32x16_bf16(ca1, bf, acc[1][pt], 0, 0, 0);
        }
        if (t < 8) { ca0 = na0; ca1 = na1; }
    }
    __builtin_amdgcn_s_setprio(0);
}

__global__ __launch_bounds__(256, 3) void k_conv2(const ushort_t* __restrict__ in,
                                                  const ushort_t* __restrict__ zv,
                                                  const ushort_t* __restrict__ wp,
                                                  const float* __restrict__ bias,
                                                  ushort_t* __restrict__ outp) {
    __shared__ __align__(16) ushort_t xs[2 * BUF_SHORTS];
    const int tid = threadIdx.x;
    const int lane = tid & 63;
    const int wv = tid >> 6;
    const unsigned bid = blockIdx.x;
    const unsigned L = (bid & 7u) * 512u + (bid >> 3);
    const int h = L & 255, b = L >> 8;
    const int l31 = lane & 31, lhi = lane >> 5;
    const int pw0 = wv * 64;

    const ushort_t* rb0 = (h > 0)   ? in + ((size_t)(b * 256 + h - 1)) * 16384 : zv;
    const ushort_t* rb1 =             in + ((size_t)(b * 256 + h)) * 16384;
    const ushort_t* rb2 = (h < 255) ? in + ((size_t)(b * 256 + h + 1)) * 16384 : zv;

    f32x16 acc[2][2];
#pragma unroll
    for (int a = 0; a < 2; ++a)
#pragma unroll
        for (int c = 0; c < 2; ++c) acc[a][c] = (f32x16)0.0f;

    short8 pa0, pa1;
    apre2(wp, 0, lane, pa0, pa1);
    PIN();
    STAGE_CHUNK(0, 0);
    STAGE_CHUNK(1, BUF_SHORTS);
    VMCNT(7);   // retire A(2)+stage0(7); leave stage1(7)
    RBAR();
    compute2(wp, xs, 0, 0, lane, pw0, l31, lhi, pa0, pa1, acc);
    apre2(wp, 1, lane, pa0, pa1);
    PIN();
    RBAR();
    STAGE_CHUNK(2, 0);
    VMCNT(9);   // retire stage1(7); leave A(2)+stage2(7)
    RBAR();
    compute2(wp, xs, BUF_SHORTS, 1, lane, pw0, l31, lhi, pa0, pa1, acc);
    apre2(wp, 2, lane, pa0, pa1);
    PIN();
    RBAR();
    STAGE_CHUNK(3, BUF_SHORTS);
    VMCNT(9);
    RBAR();
    compute2(wp, xs, 0, 2, lane, pw0, l31, lhi, pa0, pa1, acc);
    apre2(wp, 3, lane, pa0, pa1);
    PIN();
    RBAR();
    VMCNT(2);   // retire stage3(7); leave A(2)
    RBAR();
    compute2(wp, xs, BUF_SHORTS, 3, lane, pw0, l31, lhi, pa0, pa1, acc);

    const int co_b = 4 * lhi;
    // bf16 NCHW: per (c), half-wave writes 32 consecutive pix (64 B).
    ushort_t* pb = outp + (((size_t)b * 64) << 16) + h * 256;
#pragma unroll
    for (int ct = 0; ct < 2; ++ct)
#pragma unroll
        for (int pt = 0; pt < 2; ++pt) {
            int pix = pw0 + pt * 32 + l31;
#pragma unroll
            for (int q = 0; q < 4; ++q) {
                float4v bv = *(const float4v*)(bias + ct * 32 + co_b + 8 * q);
#pragma unroll
                for (int m = 0; m < 4; ++m) {
                    int c = ct * 32 + co_b + 8 * q + m;
                    float v = lrelu(acc[ct][pt][q * 4 + m] + bv[m]);
                    pb[((size_t)c << 16) + pix] = f2bf(v);
                }
            }
        }
}

// ---------------------------------------------------------------------------
// Final depthwise: out[b][c][h][w] += sum_tap ktr[b][tap][c] * f2[b][c][h'][w']
// Block = (b, c, 8-row band); f2 is bf16 NCHW.
// ---------------------------------------------------------------------------
__global__ __launch_bounds__(256) void k_fin(const ushort_t* __restrict__ f2,
                                             const float* __restrict__ ktr,
                                             float* __restrict__ out) {
    __shared__ __align__(16) ushort_t s[10 * 272];
    const unsigned bid = blockIdx.x;
    const unsigned L = (bid & 7u) * 4096u + (bid >> 3);  // bijective, 32768=8*4096
    const int hb = L & 31, c = (L >> 5) & 63, b = L >> 11;
    const int h0 = hb * 8;
    const int w = threadIdx.x;

    const ushort_t* f2c = f2 + (((size_t)(b * 64 + c)) << 16);
    for (int i = w; i < 320; i += 256) {
        int r = i >> 5, seg = i & 31;
        int hs = h0 - 1 + r;
        short8 v = (short8)0;
        if ((unsigned)hs < 256u) v = *(const short8*)(f2c + hs * 256 + seg * 8);
        *(short8*)(&s[r * 272 + 8 + seg * 8]) = v;
        if (seg == 0) s[r * 272 + 7] = 0;
        if (seg == 31) s[r * 272 + 264] = 0;
    }
    __syncthreads();

    float kv[9];
#pragma unroll
    for (int t9 = 0; t9 < 9; ++t9) kv[t9] = ktr[b * 576 + t9 * 64 + c];

    float lv[10], cv[10], rv[10];
#pragma unroll
    for (int r = 0; r < 10; ++r) {
        lv[r] = bf2f(s[r * 272 + 7 + w]);
        cv[r] = bf2f(s[r * 272 + 8 + w]);
        rv[r] = bf2f(s[r * 272 + 9 + w]);
    }

    float* ob = out + (((size_t)(b * 64 + c)) << 16) + h0 * 256 + w;
#pragma unroll
    for (int rr = 0; rr < 8; ++rr) {
        float dwv = 0.f;
#pragma unroll
        for (int r3 = 0; r3 < 3; ++r3) {
            dwv = fmaf(kv[r3 * 3 + 0], lv[rr + r3], dwv);
            dwv = fmaf(kv[r3 * 3 + 1], cv[rr + r3], dwv);
            dwv = fmaf(kv[r3 * 3 + 2], rv[rr + r3], dwv);
        }
        float* po = ob + rr * 256;
        *po = *po + dwv;
    }
}

// ---------------------------------------------------------------------------
extern "C" void kernel_launch(void* const* d_in, const int* in_sizes, int n_in,
                              void* d_out, int out_size, void* d_ws, size_t ws_size,
                              hipStream_t stream) {
    const float* x   = (const float*)d_in[0];
    const float* t   = (const float*)d_in[1];
    const float* tW1 = (const float*)d_in[2];
    const float* tW2 = (const float*)d_in[3];
    const float* fW1 = (const float*)d_in[4];
    const float* fb1 = (const float*)d_in[5];
    const float* fW2 = (const float*)d_in[6];
    const float* fb2 = (const float*)d_in[7];
    const float* kW1 = (const float*)d_in[8];
    const float* kW2 = (const float*)d_in[9];
    const float* cW  = (const float*)d_in[10];
    const float* cb  = (const float*)d_in[11];

    // ws: [ktr 36K @0][wp 216K @65536][zv 32K @294912]
    //     [R1 128MB @512K]  : xbf (phase 1-2), then f2 (phase 3-4)
    //     [R2 128MB @512K+128MB] : f1 (phase 2-3)
    char* ws = (char*)d_ws;
    float*    ktr  = (float*)ws;
    ushort_t* wp   = (ushort_t*)(ws + 65536);
    ushort_t* zv   = (ushort_t*)(ws + 294912);
    ushort_t* xbf  = (ushort_t*)(ws + (512u << 10));                       // R1
    ushort_t* f1bf = (ushort_t*)(ws + (512u << 10) + ((size_t)128 << 20)); // R2
    ushort_t* f2n  = xbf;  // R1 reused: xbf dead after k_conv13
    float*    out  = (float*)d_out;

    k_tiny<<<dim3(16), dim3(64), 0, stream>>>(t, tW1, tW2, kW1, kW2, ktr);
    k_zrow<<<dim3(8), dim3(256), 0, stream>>>(zv);
    k_pack<<<dim3((3 * 36864 + 255) / 256), dim3(256), 0, stream>>>(fW1, fW2, cW, wp);
    k_tr<<<dim3(4096), dim3(256), 0, stream>>>(x, xbf);

    k_conv13<<<dim3(4096), dim3(256), 0, stream>>>(
        xbf, zv, wp, wp + 2 * 36864, fb1, cb, f1bf, out);
    k_conv2<<<dim3(4096), dim3(256), 0, stream>>>(f1bf, zv, wp + 36864, fb2, f2n);
    k_fin<<<dim3(32768), dim3(256), 0, stream>>>(f2n, ktr, out);
}